// Round 4
// baseline (333.897 us; speedup 1.0000x reference)
//
#include <hip/hip_runtime.h>
#include <math.h>

#define BB 16
#define CC 6
#define QQ 256
#define TT 256
#define DD 256
#define NPAIR 15                      // C*(C-1)/2 for C=6
#define NBC (BB * CC)                 // 96
#define BIG_BLOCKS (NBC * 16)         // 1536 (16 chunks of 1024 float4 per (b,c))
#define CONS_BLOCKS (BB * NPAIR * 4)  // 960 (4 q-groups per (b,pair))
#define MAIN_BLOCKS (BIG_BLOCKS + CONS_BLOCKS)  // 2496

// ws layout (bytes) — everything written unconditionally each call, no zeroing
// (ticket counter is zeroed by k_pack, which completes before k_main starts):
//   [0,      98304)  qids int[24576]
//   [98304,  98400)  cam_c uchar[96]
//   [98432, 101504)  packPart float[96*8]  (score,box,pair,qv,cam per block)
//   [101504,101508)  ticket int
//   [101632,113920)  bigPart  float[1536*2] (ss, ent per block)
//   [113920,121600)  consPart float[960*2]  (cons, nval per block)

__device__ __forceinline__ float block_sum256(float v, float* s_red) {
    #pragma unroll
    for (int off = 32; off > 0; off >>= 1) v += __shfl_xor(v, off, 64);
    __syncthreads();
    if ((threadIdx.x & 63) == 0) s_red[threadIdx.x >> 6] = v;
    __syncthreads();
    return s_red[0] + s_red[1] + s_red[2] + s_red[3];
}

__device__ __forceinline__ int read_bool(const void* p, int idx, int fmt) {
    if (fmt == 2) return ((const float*)p)[idx] != 0.0f;
    if (fmt == 1) return ((const unsigned char*)p)[idx] != 0;
    return ((const int*)p)[idx] != 0;
}

// ---------------------------------------------------------------------------
// Kernel 1: per-(b,c) pack + score/box/pair losses + qids + cam_c.
// Each block redundantly detects the bool storage format from the first 4 KB
// of target_mask (valid window in every candidate format; L2-hot).
// Block 0 also zeroes the ticket counter for k_main.
// ---------------------------------------------------------------------------
__global__ __launch_bounds__(256)
void k_pack(const float* __restrict__ det_scores,
            const float* __restrict__ det_boxes,
            const float* __restrict__ assoc,
            const float* __restrict__ boxes,
            const void* __restrict__ cam_raw,
            const void* __restrict__ tm_raw,
            const int* __restrict__ ids,
            const int* __restrict__ img_h_p,
            const int* __restrict__ img_w_p,
            unsigned char* __restrict__ cam_c,
            int* __restrict__ qids,
            float* __restrict__ packPart,
            int* __restrict__ ticket) {
    const int bc = blockIdx.x;      // b*CC + c
    const int t = threadIdx.x;      // 0..255 (query index)
    const int lane = t & 63, wv = t >> 6;
    __shared__ int s_cf, s_cm, s_wsum[4];
    __shared__ int s_sids[QQ];
    __shared__ float s_red[4];

    if (bc == 0 && t == 0) ticket[0] = 0;   // visible to k_main via kernel-boundary release

    // --- format detection (first 4096 bytes of tm_raw) ---
    if (t == 0) { s_cf = 0; s_cm = 0; }
    __syncthreads();
    {
        uint4 w = ((const uint4*)tm_raw)[t];
        unsigned int u4[4] = {w.x, w.y, w.z, w.w};
        int cf = 0, cm = 0;
        #pragma unroll
        for (int k = 0; k < 4; k++) {
            cf += ((u4[k] >> 24) == 0x3Fu);          // 1.0f high byte
            cm += ((u4[k] & 0xFFFFFF00u) != 0u);     // nonzero misaligned byte
        }
        if (cf) atomicAdd(&s_cf, cf);
        if (cm) atomicAdd(&s_cm, cm);
    }
    __syncthreads();
    const int fmt = (s_cf > 16) ? 2 : ((s_cm > 0) ? 1 : 0);  // 2=f32 1=u8 0=i32

    const int cam = read_bool(cam_raw, bc, fmt);
    const int tm  = read_bool(tm_raw, bc * QQ + t, fmt);
    if (t == 0) cam_c[bc] = (unsigned char)cam;

    // --- stable targets-first rank via wave shfl-scan + LDS combine ---
    int v = tm;
    #pragma unroll
    for (int off = 1; off < 64; off <<= 1) {
        int u = __shfl_up(v, off, 64);
        if (lane >= off) v += u;
    }
    if (lane == 63) s_wsum[wv] = v;
    __syncthreads();
    const int count = s_wsum[0] + s_wsum[1] + s_wsum[2] + s_wsum[3];
    int woff = 0;
    #pragma unroll
    for (int k = 0; k < 3; k++) woff += (k < wv) ? s_wsum[k] : 0;
    const int excl = woff + v - tm;                      // exclusive scan of tm
    const int rank = tm ? excl : (count + (t - excl));   // stable partition rank

    s_sids[rank] = ids[bc * QQ + t];
    __syncthreads();

    // thread t plays packed-slot j = t for score/pair, original-q = t for box
    const int j = t;
    const int qv = (j < count) && cam;
    const int qid = qv ? s_sids[j] : -1;
    qids[bc * QQ + j] = qid;

    float score_sum = 0.0f, box_sum = 0.0f, pair_sum = 0.0f;

    if (cam) {
        float p = det_scores[(size_t)bc * QQ + j];
        p = fminf(fmaxf(p, 1e-6f), 1.0f - 1e-6f);
        score_sum = (j < count) ? -__logf(p) : -__logf(1.0f - p);
    }
    if (qv) {
        int slot = qid & (TT - 1);          // qid >= 0, TT power of 2
        float a = assoc[((size_t)bc * QQ + j) * TT + slot];
        pair_sum = -__logf(fmaxf(a, 1e-8f));
    }
    if (tm && cam) {
        const int jj = rank;                // packed slot of original query t
        const float iw = (float)img_w_p[0], ih = (float)img_h_p[0];
        const float* bx = boxes + ((size_t)bc * QQ + t) * 4;
        const float* db = det_boxes + ((size_t)bc * QQ + jj) * 4;
        float b0 = fminf(fmaxf(bx[0] / iw, 0.0f), 1.0f);
        float b1 = fminf(fmaxf(bx[1] / ih, 0.0f), 1.0f);
        float b2 = fminf(fmaxf(bx[2] / iw, 0.0f), 1.0f);
        float b3 = fminf(fmaxf(bx[3] / ih, 0.0f), 1.0f);
        box_sum = fabsf(db[0] - b0) + fabsf(db[1] - b1) +
                  fabsf(db[2] - b2) + fabsf(db[3] - b3);
    }

    float vs = block_sum256(score_sum, s_red);
    float vb = block_sum256(box_sum, s_red);
    float vp = block_sum256(pair_sum, s_red);
    if (t == 0) {
        float* row = packPart + bc * 8;
        row[0] = vs; row[1] = vb; row[2] = vp;
        row[3] = cam ? (float)count : 0.0f;   // qvalid count
        row[4] = (float)cam;
    }
}

// ---------------------------------------------------------------------------
// Kernel 2: fused everything-else in ONE dispatch.
//   blocks [0, 1536):    det_norm ss + cam-masked entropy (1024-float4 chunks)
//   blocks [1536, 2496): consistency term (one per (b, pair, qgroup-of-64))
//   last block to finish (ticket) reduces all partials and writes d_out.
// ---------------------------------------------------------------------------
__global__ __launch_bounds__(256)
void k_main(const float4* __restrict__ tok, const float* __restrict__ assoc,
            const unsigned char* __restrict__ cam_c,
            const int* __restrict__ qids,
            float* __restrict__ packPart, float* __restrict__ bigPart,
            float* __restrict__ consPart, int* __restrict__ ticket,
            float* __restrict__ out) {
    const int blk = blockIdx.x;
    const int t = threadIdx.x, lane = t & 63, wv = t >> 6;
    __shared__ float s_red[4];

    if (blk < BIG_BLOCKS) {
        // ---- big phase: ss + entropy over one 1024-float4 chunk ----
        const int bc = blk >> 4;
        const long base = (long)bc * 16384 + (long)(blk & 15) * 1024 + t;
        const float4* asc = (const float4*)assoc;

        float4 t0 = tok[base], t1 = tok[base + 256],
               t2 = tok[base + 512], t3 = tok[base + 768];
        float ss = t0.x * t0.x + t0.y * t0.y + t0.z * t0.z + t0.w * t0.w
                 + t1.x * t1.x + t1.y * t1.y + t1.z * t1.z + t1.w * t1.w
                 + t2.x * t2.x + t2.y * t2.y + t2.z * t2.z + t2.w * t2.w
                 + t3.x * t3.x + t3.y * t3.y + t3.z * t3.z + t3.w * t3.w;

        float ent = 0.0f;
        if (cam_c[bc]) {                      // block-uniform branch
            float4 a0 = asc[base], a1 = asc[base + 256],
                   a2 = asc[base + 512], a3 = asc[base + 768];
            ent -= a0.x * __logf(fmaxf(a0.x, 1e-8f)) + a0.y * __logf(fmaxf(a0.y, 1e-8f))
                 + a0.z * __logf(fmaxf(a0.z, 1e-8f)) + a0.w * __logf(fmaxf(a0.w, 1e-8f));
            ent -= a1.x * __logf(fmaxf(a1.x, 1e-8f)) + a1.y * __logf(fmaxf(a1.y, 1e-8f))
                 + a1.z * __logf(fmaxf(a1.z, 1e-8f)) + a1.w * __logf(fmaxf(a1.w, 1e-8f));
            ent -= a2.x * __logf(fmaxf(a2.x, 1e-8f)) + a2.y * __logf(fmaxf(a2.y, 1e-8f))
                 + a2.z * __logf(fmaxf(a2.z, 1e-8f)) + a2.w * __logf(fmaxf(a2.w, 1e-8f));
            ent -= a3.x * __logf(fmaxf(a3.x, 1e-8f)) + a3.y * __logf(fmaxf(a3.y, 1e-8f))
                 + a3.z * __logf(fmaxf(a3.z, 1e-8f)) + a3.w * __logf(fmaxf(a3.w, 1e-8f));
        }
        float vss = block_sum256(ss, s_red);
        float vent = block_sum256(ent, s_red);
        if (t == 0) { bigPart[blk * 2] = vss; bigPart[blk * 2 + 1] = vent; }
    } else {
        // ---- cons phase ----
        const int cb = blk - BIG_BLOCKS;
        const int qg = cb & 3;
        const int bp = cb >> 2;             // b*NPAIR + pair
        const int b = bp / NPAIR;
        int pi = bp % NPAIR;
        int c = 0, d = 1;
        {
            int k = pi;
            for (c = 0; c < CC - 1; c++) {
                int span = CC - 1 - c;
                if (k < span) { d = c + 1 + k; break; }
                k -= span;
            }
        }
        __shared__ int s_qc[64];
        __shared__ int s_qd[QQ];
        __shared__ int s_wnval[4];
        if (t < 64) s_qc[t] = qids[(b * CC + c) * QQ + qg * 64 + t];
        s_qd[t] = qids[(b * CC + d) * QQ + t];
        __syncthreads();

        const int qd0 = s_qd[lane];
        const int qd1 = s_qd[64 + lane];
        const int qd2 = s_qd[128 + lane];
        const int qd3 = s_qd[192 + lane];
        const float4* assoc_c = (const float4*)(assoc + (size_t)(b * CC + c) * QQ * TT);
        const float4* assoc_d = (const float4*)(assoc + (size_t)(b * CC + d) * QQ * TT);

        float tot = 0.0f;
        int nval = 0;
        for (int qi = 0; qi < 16; qi++) {
            const int qloc = wv * 16 + qi;
            const int id = s_qc[qloc];          // wave-uniform
            if (id < 0) continue;
            unsigned long long m0 = __ballot(qd0 == id);
            unsigned long long m1 = __ballot(qd1 == id);
            unsigned long long m2 = __ballot(qd2 == id);
            unsigned long long m3 = __ballot(qd3 == id);
            int cnt = __popcll(m0) + __popcll(m1) + __popcll(m2) + __popcll(m3);
            if (cnt == 0) continue;
            const int q = qg * 64 + qloc;
            float4 r = assoc_c[(size_t)q * (TT / 4) + lane];
            float ax = 0.0f, ay = 0.0f, az = 0.0f, aw = 0.0f;
            unsigned long long mm[4] = {m0, m1, m2, m3};
            #pragma unroll
            for (int kk = 0; kk < 4; kk++) {
                unsigned long long m = mm[kk];
                while (m) {
                    int p = kk * 64 + __builtin_ctzll(m);
                    m &= m - 1;
                    float4 vv = assoc_d[(size_t)p * (TT / 4) + lane];
                    ax += vv.x; ay += vv.y; az += vv.z; aw += vv.w;
                }
            }
            float inv = 1.0f / (float)cnt;
            float dx = r.x - ax * inv, dy = r.y - ay * inv;
            float dz = r.z - az * inv, dw = r.w - aw * inv;
            tot += dx * dx + dy * dy + dz * dz + dw * dw;
            nval++;
        }
        #pragma unroll
        for (int off = 32; off > 0; off >>= 1) tot += __shfl_xor(tot, off, 64);
        if (lane == 0) { s_red[wv] = tot; s_wnval[wv] = nval; }
        __syncthreads();
        if (t == 0) {
            float csum = s_red[0] + s_red[1] + s_red[2] + s_red[3];
            int n4 = s_wnval[0] + s_wnval[1] + s_wnval[2] + s_wnval[3];
            consPart[cb * 2] = csum * (1.0f / TT);
            consPart[cb * 2 + 1] = (float)n4;
        }
    }

    // ---- last-block finalize ----
    __shared__ int s_last;
    __threadfence();                        // release our partial
    __syncthreads();                        // all LDS/partial writes issued
    if (t == 0) {
        int old = atomicAdd(ticket, 1);     // device-scope
        s_last = (old == MAIN_BLOCKS - 1);
    }
    __syncthreads();
    if (!s_last) return;
    __threadfence();                        // acquire others' partials

    float sc = 0, bx = 0, pr = 0, qv = 0, cm = 0;
    if (t < NBC) {
        const float* row = packPart + t * 8;
        sc = row[0]; bx = row[1]; pr = row[2]; qv = row[3]; cm = row[4];
    }
    float ss = 0, ent = 0;
    for (int i = t; i < BIG_BLOCKS; i += 256) {
        ss += bigPart[2 * i]; ent += bigPart[2 * i + 1];
    }
    float cons = 0, nval = 0;
    for (int i = t; i < CONS_BLOCKS; i += 256) {
        cons += consPart[2 * i]; nval += consPart[2 * i + 1];
    }
    sc = block_sum256(sc, s_red);
    bx = block_sum256(bx, s_red);
    pr = block_sum256(pr, s_red);
    qv = block_sum256(qv, s_red);
    cm = block_sum256(cm, s_red);
    ss = block_sum256(ss, s_red);
    ent = block_sum256(ent, s_red);
    cons = block_sum256(cons, s_red);
    nval = block_sum256(nval, s_red);
    if (t == 0) {
        float det_norm = ss / (float)((long)BB * CC * QQ * DD);
        float denom_cam = fmaxf(cm * (float)QQ, 1.0f);
        float score_loss = sc / denom_cam;
        float box_loss = bx / fmaxf(4.0f * qv, 1.0f);
        float det_sup = score_loss + box_loss;
        float ent_loss = ent / denom_cam;
        float pair_loss = pr / fmaxf(qv, 1.0f);
        float cons_loss = cons / fmaxf(nval, 1.0f);
        out[0] = det_norm + det_sup + ent_loss + pair_loss + cons_loss;
        out[1] = det_norm;
        out[2] = det_sup;
        out[3] = ent_loss;
        out[4] = pair_loss;
        out[5] = cons_loss;
    }
}

extern "C" void kernel_launch(void* const* d_in, const int* in_sizes, int n_in,
                              void* d_out, int out_size, void* d_ws, size_t ws_size,
                              hipStream_t stream) {
    const float* det_tokens = (const float*)d_in[0];
    const float* det_scores = (const float*)d_in[1];
    const float* det_boxes  = (const float*)d_in[2];
    const float* assoc      = (const float*)d_in[3];
    const float* boxes      = (const float*)d_in[4];
    const void*  cam_raw    = d_in[5];
    const void*  tm_raw     = d_in[6];
    const int*   ids        = (const int*)d_in[7];
    const int*   img_h      = (const int*)d_in[8];
    const int*   img_w      = (const int*)d_in[9];

    char* ws = (char*)d_ws;
    int* qids            = (int*)(ws + 0);
    unsigned char* cam_c = (unsigned char*)(ws + 98304);
    float* packPart      = (float*)(ws + 98432);
    int* ticket          = (int*)(ws + 101504);
    float* bigPart       = (float*)(ws + 101632);
    float* consPart      = (float*)(ws + 113920);

    k_pack<<<NBC, 256, 0, stream>>>(det_scores, det_boxes, assoc, boxes,
                                    cam_raw, tm_raw, ids, img_h, img_w,
                                    cam_c, qids, packPart, ticket);
    k_main<<<MAIN_BLOCKS, 256, 0, stream>>>((const float4*)det_tokens, assoc,
                                            cam_c, qids, packPart, bigPart,
                                            consPart, ticket, (float*)d_out);
}

// Round 5
// 154.387 us; speedup vs baseline: 2.1627x; 2.1627x over previous
//
#include <hip/hip_runtime.h>
#include <math.h>

#define BB 16
#define CC 6
#define QQ 256
#define TT 256
#define DD 256
#define NPAIR 15                      // C*(C-1)/2 for C=6
#define NBC (BB * CC)                 // 96
#define BIG_BLOCKS (NBC * 16)         // 1536 (16 chunks of 1024 float4 per (b,c))
#define CONS_BLOCKS (BB * NPAIR * 4)  // 960 (4 q-groups per (b,pair))
#define MAIN_BLOCKS (BIG_BLOCKS + CONS_BLOCKS)  // 2496

// scalar accumulator slots (zeroed by k_pack block 0; filled by k_main atomics)
#define ACC_SS      0
#define ACC_ENT     1
#define ACC_CONS    2
#define ACC_CONSCNT 3

// ws layout (bytes):
//   [0,      98304)  qids int[24576]
//   [98304,  98400)  cam_c uchar[96]
//   [98432, 101504)  packPart float[96*8]  (score,box,pair,qv,cam per block)
//   [101504,101568)  acc float[16]
// NOTE (R4 post-mortem): never publish cross-block results with plain store +
// __threadfence + ticket on gfx950 — device-scope fence = L2 writeback, and
// 2496 of them cost ~270 us. Device-scope atomicAdd + kernel boundary is free.

__device__ __forceinline__ float block_sum256(float v, float* s_red) {
    #pragma unroll
    for (int off = 32; off > 0; off >>= 1) v += __shfl_xor(v, off, 64);
    __syncthreads();
    if ((threadIdx.x & 63) == 0) s_red[threadIdx.x >> 6] = v;
    __syncthreads();
    return s_red[0] + s_red[1] + s_red[2] + s_red[3];
}

__device__ __forceinline__ int read_bool(const void* p, int idx, int fmt) {
    if (fmt == 2) return ((const float*)p)[idx] != 0.0f;
    if (fmt == 1) return ((const unsigned char*)p)[idx] != 0;
    return ((const int*)p)[idx] != 0;
}

// ---------------------------------------------------------------------------
// Kernel 1: per-(b,c) pack + score/box/pair losses + qids + cam_c.
// Each block redundantly detects the bool storage format from the first 4 KB
// of target_mask (valid window in every candidate format; L2-hot).
// Block 0 zeroes the scalar accumulators for k_main's atomics.
// ---------------------------------------------------------------------------
__global__ __launch_bounds__(256)
void k_pack(const float* __restrict__ det_scores,
            const float* __restrict__ det_boxes,
            const float* __restrict__ assoc,
            const float* __restrict__ boxes,
            const void* __restrict__ cam_raw,
            const void* __restrict__ tm_raw,
            const int* __restrict__ ids,
            const int* __restrict__ img_h_p,
            const int* __restrict__ img_w_p,
            unsigned char* __restrict__ cam_c,
            int* __restrict__ qids,
            float* __restrict__ packPart,
            float* __restrict__ acc) {
    const int bc = blockIdx.x;      // b*CC + c
    const int t = threadIdx.x;      // 0..255 (query index)
    const int lane = t & 63, wv = t >> 6;
    __shared__ int s_cf, s_cm, s_wsum[4];
    __shared__ int s_sids[QQ];
    __shared__ float s_red[4];

    if (bc == 0 && t < 16) acc[t] = 0.0f;   // visible to k_main via kernel boundary

    // --- format detection (first 4096 bytes of tm_raw) ---
    if (t == 0) { s_cf = 0; s_cm = 0; }
    __syncthreads();
    {
        uint4 w = ((const uint4*)tm_raw)[t];
        unsigned int u4[4] = {w.x, w.y, w.z, w.w};
        int cf = 0, cm = 0;
        #pragma unroll
        for (int k = 0; k < 4; k++) {
            cf += ((u4[k] >> 24) == 0x3Fu);          // 1.0f high byte
            cm += ((u4[k] & 0xFFFFFF00u) != 0u);     // nonzero misaligned byte
        }
        if (cf) atomicAdd(&s_cf, cf);
        if (cm) atomicAdd(&s_cm, cm);
    }
    __syncthreads();
    const int fmt = (s_cf > 16) ? 2 : ((s_cm > 0) ? 1 : 0);  // 2=f32 1=u8 0=i32

    const int cam = read_bool(cam_raw, bc, fmt);
    const int tm  = read_bool(tm_raw, bc * QQ + t, fmt);
    if (t == 0) cam_c[bc] = (unsigned char)cam;

    // --- stable targets-first rank via wave shfl-scan + LDS combine ---
    int v = tm;
    #pragma unroll
    for (int off = 1; off < 64; off <<= 1) {
        int u = __shfl_up(v, off, 64);
        if (lane >= off) v += u;
    }
    if (lane == 63) s_wsum[wv] = v;
    __syncthreads();
    const int count = s_wsum[0] + s_wsum[1] + s_wsum[2] + s_wsum[3];
    int woff = 0;
    #pragma unroll
    for (int k = 0; k < 3; k++) woff += (k < wv) ? s_wsum[k] : 0;
    const int excl = woff + v - tm;                      // exclusive scan of tm
    const int rank = tm ? excl : (count + (t - excl));   // stable partition rank

    s_sids[rank] = ids[bc * QQ + t];
    __syncthreads();

    // thread t plays packed-slot j = t for score/pair, original-q = t for box
    const int j = t;
    const int qv = (j < count) && cam;
    const int qid = qv ? s_sids[j] : -1;
    qids[bc * QQ + j] = qid;

    float score_sum = 0.0f, box_sum = 0.0f, pair_sum = 0.0f;

    if (cam) {
        float p = det_scores[(size_t)bc * QQ + j];
        p = fminf(fmaxf(p, 1e-6f), 1.0f - 1e-6f);
        score_sum = (j < count) ? -__logf(p) : -__logf(1.0f - p);
    }
    if (qv) {
        int slot = qid & (TT - 1);          // qid >= 0, TT power of 2
        float a = assoc[((size_t)bc * QQ + j) * TT + slot];
        pair_sum = -__logf(fmaxf(a, 1e-8f));
    }
    if (tm && cam) {
        const int jj = rank;                // packed slot of original query t
        const float iw = (float)img_w_p[0], ih = (float)img_h_p[0];
        const float* bx = boxes + ((size_t)bc * QQ + t) * 4;
        const float* db = det_boxes + ((size_t)bc * QQ + jj) * 4;
        float b0 = fminf(fmaxf(bx[0] / iw, 0.0f), 1.0f);
        float b1 = fminf(fmaxf(bx[1] / ih, 0.0f), 1.0f);
        float b2 = fminf(fmaxf(bx[2] / iw, 0.0f), 1.0f);
        float b3 = fminf(fmaxf(bx[3] / ih, 0.0f), 1.0f);
        box_sum = fabsf(db[0] - b0) + fabsf(db[1] - b1) +
                  fabsf(db[2] - b2) + fabsf(db[3] - b3);
    }

    float vs = block_sum256(score_sum, s_red);
    float vb = block_sum256(box_sum, s_red);
    float vp = block_sum256(pair_sum, s_red);
    if (t == 0) {
        float* row = packPart + bc * 8;
        row[0] = vs; row[1] = vb; row[2] = vp;
        row[3] = cam ? (float)count : 0.0f;   // qvalid count
        row[4] = (float)cam;
    }
}

// ---------------------------------------------------------------------------
// Kernel 2: big + cons fused in one dispatch; partials published via
// device-scope atomicAdd (fence-free; consumer is the next kernel).
//   blocks [0, 1536):    det_norm ss + cam-masked entropy (1024-float4 chunks)
//   blocks [1536, 2496): consistency term (one per (b, pair, qgroup-of-64))
// ---------------------------------------------------------------------------
__global__ __launch_bounds__(256)
void k_main(const float4* __restrict__ tok, const float* __restrict__ assoc,
            const unsigned char* __restrict__ cam_c,
            const int* __restrict__ qids,
            float* __restrict__ acc) {
    const int blk = blockIdx.x;
    const int t = threadIdx.x, lane = t & 63, wv = t >> 6;
    __shared__ float s_red[4];

    if (blk < BIG_BLOCKS) {
        // ---- big phase: ss + entropy over one 1024-float4 chunk ----
        const int bc = blk >> 4;
        const long base = (long)bc * 16384 + (long)(blk & 15) * 1024 + t;
        const float4* asc = (const float4*)assoc;

        float4 t0 = tok[base], t1 = tok[base + 256],
               t2 = tok[base + 512], t3 = tok[base + 768];
        float ss = t0.x * t0.x + t0.y * t0.y + t0.z * t0.z + t0.w * t0.w
                 + t1.x * t1.x + t1.y * t1.y + t1.z * t1.z + t1.w * t1.w
                 + t2.x * t2.x + t2.y * t2.y + t2.z * t2.z + t2.w * t2.w
                 + t3.x * t3.x + t3.y * t3.y + t3.z * t3.z + t3.w * t3.w;

        float ent = 0.0f;
        if (cam_c[bc]) {                      // block-uniform branch
            float4 a0 = asc[base], a1 = asc[base + 256],
                   a2 = asc[base + 512], a3 = asc[base + 768];
            ent -= a0.x * __logf(fmaxf(a0.x, 1e-8f)) + a0.y * __logf(fmaxf(a0.y, 1e-8f))
                 + a0.z * __logf(fmaxf(a0.z, 1e-8f)) + a0.w * __logf(fmaxf(a0.w, 1e-8f));
            ent -= a1.x * __logf(fmaxf(a1.x, 1e-8f)) + a1.y * __logf(fmaxf(a1.y, 1e-8f))
                 + a1.z * __logf(fmaxf(a1.z, 1e-8f)) + a1.w * __logf(fmaxf(a1.w, 1e-8f));
            ent -= a2.x * __logf(fmaxf(a2.x, 1e-8f)) + a2.y * __logf(fmaxf(a2.y, 1e-8f))
                 + a2.z * __logf(fmaxf(a2.z, 1e-8f)) + a2.w * __logf(fmaxf(a2.w, 1e-8f));
            ent -= a3.x * __logf(fmaxf(a3.x, 1e-8f)) + a3.y * __logf(fmaxf(a3.y, 1e-8f))
                 + a3.z * __logf(fmaxf(a3.z, 1e-8f)) + a3.w * __logf(fmaxf(a3.w, 1e-8f));
        }
        float vss = block_sum256(ss, s_red);
        float vent = block_sum256(ent, s_red);
        if (t == 0) {
            if (vss != 0.0f) atomicAdd(&acc[ACC_SS], vss);
            if (vent != 0.0f) atomicAdd(&acc[ACC_ENT], vent);
        }
    } else {
        // ---- cons phase ----
        const int cb = blk - BIG_BLOCKS;
        const int qg = cb & 3;
        const int bp = cb >> 2;             // b*NPAIR + pair
        const int b = bp / NPAIR;
        int pi = bp % NPAIR;
        int c = 0, d = 1;
        {
            int k = pi;
            for (c = 0; c < CC - 1; c++) {
                int span = CC - 1 - c;
                if (k < span) { d = c + 1 + k; break; }
                k -= span;
            }
        }
        __shared__ int s_qc[64];
        __shared__ int s_qd[QQ];
        __shared__ int s_wnval[4];
        if (t < 64) s_qc[t] = qids[(b * CC + c) * QQ + qg * 64 + t];
        s_qd[t] = qids[(b * CC + d) * QQ + t];
        __syncthreads();

        const int qd0 = s_qd[lane];
        const int qd1 = s_qd[64 + lane];
        const int qd2 = s_qd[128 + lane];
        const int qd3 = s_qd[192 + lane];
        const float4* assoc_c = (const float4*)(assoc + (size_t)(b * CC + c) * QQ * TT);
        const float4* assoc_d = (const float4*)(assoc + (size_t)(b * CC + d) * QQ * TT);

        float tot = 0.0f;
        int nval = 0;
        for (int qi = 0; qi < 16; qi++) {
            const int qloc = wv * 16 + qi;
            const int id = s_qc[qloc];          // wave-uniform
            if (id < 0) continue;
            unsigned long long m0 = __ballot(qd0 == id);
            unsigned long long m1 = __ballot(qd1 == id);
            unsigned long long m2 = __ballot(qd2 == id);
            unsigned long long m3 = __ballot(qd3 == id);
            int cnt = __popcll(m0) + __popcll(m1) + __popcll(m2) + __popcll(m3);
            if (cnt == 0) continue;
            const int q = qg * 64 + qloc;
            float4 r = assoc_c[(size_t)q * (TT / 4) + lane];
            float ax = 0.0f, ay = 0.0f, az = 0.0f, aw = 0.0f;
            unsigned long long mm[4] = {m0, m1, m2, m3};
            #pragma unroll
            for (int kk = 0; kk < 4; kk++) {
                unsigned long long m = mm[kk];
                while (m) {
                    int p = kk * 64 + __builtin_ctzll(m);
                    m &= m - 1;
                    float4 vv = assoc_d[(size_t)p * (TT / 4) + lane];
                    ax += vv.x; ay += vv.y; az += vv.z; aw += vv.w;
                }
            }
            float inv = 1.0f / (float)cnt;
            float dx = r.x - ax * inv, dy = r.y - ay * inv;
            float dz = r.z - az * inv, dw = r.w - aw * inv;
            tot += dx * dx + dy * dy + dz * dz + dw * dw;
            nval++;
        }
        #pragma unroll
        for (int off = 32; off > 0; off >>= 1) tot += __shfl_xor(tot, off, 64);
        if (lane == 0) { s_red[wv] = tot; s_wnval[wv] = nval; }
        __syncthreads();
        if (t == 0) {
            float csum = s_red[0] + s_red[1] + s_red[2] + s_red[3];
            int n4 = s_wnval[0] + s_wnval[1] + s_wnval[2] + s_wnval[3];
            if (csum != 0.0f) atomicAdd(&acc[ACC_CONS], csum * (1.0f / TT));
            if (n4) atomicAdd(&acc[ACC_CONSCNT], (float)n4);
        }
    }
}

// ---------------------------------------------------------------------------
// Kernel 3: finalize — reduce 96 packPart rows + 4 atomic scalars.
// ---------------------------------------------------------------------------
__global__ __launch_bounds__(256)
void k_fin(const float* __restrict__ packPart, const float* __restrict__ acc,
           float* __restrict__ out) {
    const int t = threadIdx.x;
    __shared__ float s_red[4];
    float sc = 0, bx = 0, pr = 0, qv = 0, cm = 0;
    if (t < NBC) {
        const float* row = packPart + t * 8;
        sc = row[0]; bx = row[1]; pr = row[2]; qv = row[3]; cm = row[4];
    }
    sc = block_sum256(sc, s_red);
    bx = block_sum256(bx, s_red);
    pr = block_sum256(pr, s_red);
    qv = block_sum256(qv, s_red);
    cm = block_sum256(cm, s_red);
    if (t == 0) {
        float ss = acc[ACC_SS], ent = acc[ACC_ENT];
        float cons = acc[ACC_CONS], nval = acc[ACC_CONSCNT];
        float det_norm = ss / (float)((long)BB * CC * QQ * DD);
        float denom_cam = fmaxf(cm * (float)QQ, 1.0f);
        float score_loss = sc / denom_cam;
        float box_loss = bx / fmaxf(4.0f * qv, 1.0f);
        float det_sup = score_loss + box_loss;
        float ent_loss = ent / denom_cam;
        float pair_loss = pr / fmaxf(qv, 1.0f);
        float cons_loss = cons / fmaxf(nval, 1.0f);
        out[0] = det_norm + det_sup + ent_loss + pair_loss + cons_loss;
        out[1] = det_norm;
        out[2] = det_sup;
        out[3] = ent_loss;
        out[4] = pair_loss;
        out[5] = cons_loss;
    }
}

extern "C" void kernel_launch(void* const* d_in, const int* in_sizes, int n_in,
                              void* d_out, int out_size, void* d_ws, size_t ws_size,
                              hipStream_t stream) {
    const float* det_tokens = (const float*)d_in[0];
    const float* det_scores = (const float*)d_in[1];
    const float* det_boxes  = (const float*)d_in[2];
    const float* assoc      = (const float*)d_in[3];
    const float* boxes      = (const float*)d_in[4];
    const void*  cam_raw    = d_in[5];
    const void*  tm_raw     = d_in[6];
    const int*   ids        = (const int*)d_in[7];
    const int*   img_h      = (const int*)d_in[8];
    const int*   img_w      = (const int*)d_in[9];

    char* ws = (char*)d_ws;
    int* qids            = (int*)(ws + 0);
    unsigned char* cam_c = (unsigned char*)(ws + 98304);
    float* packPart      = (float*)(ws + 98432);
    float* acc           = (float*)(ws + 101504);

    k_pack<<<NBC, 256, 0, stream>>>(det_scores, det_boxes, assoc, boxes,
                                    cam_raw, tm_raw, ids, img_h, img_w,
                                    cam_c, qids, packPart, acc);
    k_main<<<MAIN_BLOCKS, 256, 0, stream>>>((const float4*)det_tokens, assoc,
                                            cam_c, qids, acc);
    k_fin<<<1, 256, 0, stream>>>(packPart, acc, (float*)d_out);
}

// Round 6
// 117.255 us; speedup vs baseline: 2.8476x; 1.3167x over previous
//
#include <hip/hip_runtime.h>
#include <math.h>

#define BB 16
#define CC 6
#define QQ 256
#define TT 256
#define DD 256
#define NPAIR 15                      // C*(C-1)/2 for C=6
#define NBC (BB * CC)                 // 96
#define BIG_BLOCKS (NBC * 16)         // 1536 (16 chunks of 1024 float4 per (b,c))
#define CONS_BLOCKS (BB * NPAIR * 4)  // 960 (4 q-groups per (b,pair))
#define MAIN_BLOCKS (BIG_BLOCKS + CONS_BLOCKS)  // 2496

// ws layout (bytes) — all partials are DISJOINT plain stores, consumed by the
// next dispatch (kernel-boundary coherence). R4 post-mortem: device-scope
// __threadfence costs ~100 ns × blocks (L2 writeback). R5 post-mortem:
// same-address float atomics from 2496 blocks serialize (~+35 us). Disjoint
// stores + kernel boundary is the only free publication path on gfx950.
//   [0,      98304)  qids int[24576]
//   [98304,  98400)  cam_c uchar[96]
//   [98432, 101504)  packPart float[96*8]  (score,box,pair,qv,cam per block)
//   [101504,113792)  bigPart  float[1536*2] (ss, ent per block)
//   [113792,121472)  consPart float[960*2]  (cons, nval per block)

__device__ __forceinline__ float block_sum256(float v, float* s_red) {
    #pragma unroll
    for (int off = 32; off > 0; off >>= 1) v += __shfl_xor(v, off, 64);
    __syncthreads();
    if ((threadIdx.x & 63) == 0) s_red[threadIdx.x >> 6] = v;
    __syncthreads();
    return s_red[0] + s_red[1] + s_red[2] + s_red[3];
}

// two values reduced with a single pair of barriers
__device__ __forceinline__ float2 block_sum256x2(float a, float b, float2* s_red2) {
    #pragma unroll
    for (int off = 32; off > 0; off >>= 1) {
        a += __shfl_xor(a, off, 64);
        b += __shfl_xor(b, off, 64);
    }
    __syncthreads();
    if ((threadIdx.x & 63) == 0) s_red2[threadIdx.x >> 6] = make_float2(a, b);
    __syncthreads();
    float2 r;
    r.x = s_red2[0].x + s_red2[1].x + s_red2[2].x + s_red2[3].x;
    r.y = s_red2[0].y + s_red2[1].y + s_red2[2].y + s_red2[3].y;
    return r;
}

__device__ __forceinline__ int read_bool(const void* p, int idx, int fmt) {
    if (fmt == 2) return ((const float*)p)[idx] != 0.0f;
    if (fmt == 1) return ((const unsigned char*)p)[idx] != 0;
    return ((const int*)p)[idx] != 0;
}

// ---------------------------------------------------------------------------
// Kernel 1: per-(b,c) pack + score/box/pair losses + qids + cam_c.
// Each block redundantly detects the bool storage format from the first 4 KB
// of target_mask (valid window in every candidate format; L2-hot).
// ---------------------------------------------------------------------------
__global__ __launch_bounds__(256)
void k_pack(const float* __restrict__ det_scores,
            const float* __restrict__ det_boxes,
            const float* __restrict__ assoc,
            const float* __restrict__ boxes,
            const void* __restrict__ cam_raw,
            const void* __restrict__ tm_raw,
            const int* __restrict__ ids,
            const int* __restrict__ img_h_p,
            const int* __restrict__ img_w_p,
            unsigned char* __restrict__ cam_c,
            int* __restrict__ qids,
            float* __restrict__ packPart) {
    const int bc = blockIdx.x;      // b*CC + c
    const int t = threadIdx.x;      // 0..255 (query index)
    const int lane = t & 63, wv = t >> 6;
    __shared__ int s_cf, s_cm, s_wsum[4];
    __shared__ int s_sids[QQ];
    __shared__ float s_red[4];

    // --- format detection (first 4096 bytes of tm_raw) ---
    if (t == 0) { s_cf = 0; s_cm = 0; }
    __syncthreads();
    {
        uint4 w = ((const uint4*)tm_raw)[t];
        unsigned int u4[4] = {w.x, w.y, w.z, w.w};
        int cf = 0, cm = 0;
        #pragma unroll
        for (int k = 0; k < 4; k++) {
            cf += ((u4[k] >> 24) == 0x3Fu);          // 1.0f high byte
            cm += ((u4[k] & 0xFFFFFF00u) != 0u);     // nonzero misaligned byte
        }
        if (cf) atomicAdd(&s_cf, cf);
        if (cm) atomicAdd(&s_cm, cm);
    }
    __syncthreads();
    const int fmt = (s_cf > 16) ? 2 : ((s_cm > 0) ? 1 : 0);  // 2=f32 1=u8 0=i32

    const int cam = read_bool(cam_raw, bc, fmt);
    const int tm  = read_bool(tm_raw, bc * QQ + t, fmt);
    if (t == 0) cam_c[bc] = (unsigned char)cam;

    // --- stable targets-first rank via wave shfl-scan + LDS combine ---
    int v = tm;
    #pragma unroll
    for (int off = 1; off < 64; off <<= 1) {
        int u = __shfl_up(v, off, 64);
        if (lane >= off) v += u;
    }
    if (lane == 63) s_wsum[wv] = v;
    __syncthreads();
    const int count = s_wsum[0] + s_wsum[1] + s_wsum[2] + s_wsum[3];
    int woff = 0;
    #pragma unroll
    for (int k = 0; k < 3; k++) woff += (k < wv) ? s_wsum[k] : 0;
    const int excl = woff + v - tm;                      // exclusive scan of tm
    const int rank = tm ? excl : (count + (t - excl));   // stable partition rank

    s_sids[rank] = ids[bc * QQ + t];
    __syncthreads();

    // thread t plays packed-slot j = t for score/pair, original-q = t for box
    const int j = t;
    const int qv = (j < count) && cam;
    const int qid = qv ? s_sids[j] : -1;
    qids[bc * QQ + j] = qid;

    float score_sum = 0.0f, box_sum = 0.0f, pair_sum = 0.0f;

    if (cam) {
        float p = det_scores[(size_t)bc * QQ + j];
        p = fminf(fmaxf(p, 1e-6f), 1.0f - 1e-6f);
        score_sum = (j < count) ? -__logf(p) : -__logf(1.0f - p);
    }
    if (qv) {
        int slot = qid & (TT - 1);          // qid >= 0, TT power of 2
        float a = assoc[((size_t)bc * QQ + j) * TT + slot];
        pair_sum = -__logf(fmaxf(a, 1e-8f));
    }
    if (tm && cam) {
        const int jj = rank;                // packed slot of original query t
        const float iw = (float)img_w_p[0], ih = (float)img_h_p[0];
        const float* bx = boxes + ((size_t)bc * QQ + t) * 4;
        const float* db = det_boxes + ((size_t)bc * QQ + jj) * 4;
        float b0 = fminf(fmaxf(bx[0] / iw, 0.0f), 1.0f);
        float b1 = fminf(fmaxf(bx[1] / ih, 0.0f), 1.0f);
        float b2 = fminf(fmaxf(bx[2] / iw, 0.0f), 1.0f);
        float b3 = fminf(fmaxf(bx[3] / ih, 0.0f), 1.0f);
        box_sum = fabsf(db[0] - b0) + fabsf(db[1] - b1) +
                  fabsf(db[2] - b2) + fabsf(db[3] - b3);
    }

    float vs = block_sum256(score_sum, s_red);
    float vb = block_sum256(box_sum, s_red);
    float vp = block_sum256(pair_sum, s_red);
    if (t == 0) {
        float* row = packPart + bc * 8;
        row[0] = vs; row[1] = vb; row[2] = vp;
        row[3] = cam ? (float)count : 0.0f;   // qvalid count
        row[4] = (float)cam;
    }
}

// ---------------------------------------------------------------------------
// Kernel 2: big + cons fused; partials are disjoint plain stores.
//   blocks [0, 1536):    det_norm ss + cam-masked entropy (1024-float4 chunks)
//   blocks [1536, 2496): consistency term (one per (b, pair, qgroup-of-64))
// ---------------------------------------------------------------------------
__global__ __launch_bounds__(256)
void k_main(const float4* __restrict__ tok, const float* __restrict__ assoc,
            const unsigned char* __restrict__ cam_c,
            const int* __restrict__ qids,
            float* __restrict__ bigPart, float* __restrict__ consPart) {
    const int blk = blockIdx.x;
    const int t = threadIdx.x, lane = t & 63, wv = t >> 6;
    __shared__ float2 s_red2[4];

    if (blk < BIG_BLOCKS) {
        // ---- big phase ----
        const int bc = blk >> 4;
        const long base = (long)bc * 16384 + (long)(blk & 15) * 1024 + t;
        const float4* asc = (const float4*)assoc;

        // issue ALL loads up front (cam branch only guards the log math)
        float4 t0 = tok[base], t1 = tok[base + 256],
               t2 = tok[base + 512], t3 = tok[base + 768];
        float4 a0 = asc[base], a1 = asc[base + 256],
               a2 = asc[base + 512], a3 = asc[base + 768];
        const int cam = cam_c[bc];

        float ss = t0.x * t0.x + t0.y * t0.y + t0.z * t0.z + t0.w * t0.w
                 + t1.x * t1.x + t1.y * t1.y + t1.z * t1.z + t1.w * t1.w
                 + t2.x * t2.x + t2.y * t2.y + t2.z * t2.z + t2.w * t2.w
                 + t3.x * t3.x + t3.y * t3.y + t3.z * t3.z + t3.w * t3.w;

        float ent = 0.0f;
        if (cam) {                            // block-uniform branch
            ent -= a0.x * __logf(fmaxf(a0.x, 1e-8f)) + a0.y * __logf(fmaxf(a0.y, 1e-8f))
                 + a0.z * __logf(fmaxf(a0.z, 1e-8f)) + a0.w * __logf(fmaxf(a0.w, 1e-8f));
            ent -= a1.x * __logf(fmaxf(a1.x, 1e-8f)) + a1.y * __logf(fmaxf(a1.y, 1e-8f))
                 + a1.z * __logf(fmaxf(a1.z, 1e-8f)) + a1.w * __logf(fmaxf(a1.w, 1e-8f));
            ent -= a2.x * __logf(fmaxf(a2.x, 1e-8f)) + a2.y * __logf(fmaxf(a2.y, 1e-8f))
                 + a2.z * __logf(fmaxf(a2.z, 1e-8f)) + a2.w * __logf(fmaxf(a2.w, 1e-8f));
            ent -= a3.x * __logf(fmaxf(a3.x, 1e-8f)) + a3.y * __logf(fmaxf(a3.y, 1e-8f))
                 + a3.z * __logf(fmaxf(a3.z, 1e-8f)) + a3.w * __logf(fmaxf(a3.w, 1e-8f));
        }
        float2 r = block_sum256x2(ss, ent, s_red2);
        if (t == 0) { bigPart[blk * 2] = r.x; bigPart[blk * 2 + 1] = r.y; }
    } else {
        // ---- cons phase ----
        const int cb = blk - BIG_BLOCKS;
        const int qg = cb & 3;
        const int bp = cb >> 2;             // b*NPAIR + pair
        const int b = bp / NPAIR;
        int pi = bp % NPAIR;
        int c = 0, d = 1;
        {
            int k = pi;
            for (c = 0; c < CC - 1; c++) {
                int span = CC - 1 - c;
                if (k < span) { d = c + 1 + k; break; }
                k -= span;
            }
        }
        __shared__ int s_qc[64];
        __shared__ int s_qd[QQ];
        if (t < 64) s_qc[t] = qids[(b * CC + c) * QQ + qg * 64 + t];
        s_qd[t] = qids[(b * CC + d) * QQ + t];
        __syncthreads();

        const int qd0 = s_qd[lane];
        const int qd1 = s_qd[64 + lane];
        const int qd2 = s_qd[128 + lane];
        const int qd3 = s_qd[192 + lane];
        // preload this wave's 16 wave-uniform q-ids in one batch
        int idarr[16];
        #pragma unroll
        for (int qi = 0; qi < 16; qi++) idarr[qi] = s_qc[wv * 16 + qi];

        const float4* assoc_c = (const float4*)(assoc + (size_t)(b * CC + c) * QQ * TT);
        const float4* assoc_d = (const float4*)(assoc + (size_t)(b * CC + d) * QQ * TT);

        float tot = 0.0f;
        float nval = 0.0f;
        #pragma unroll 4
        for (int qi = 0; qi < 16; qi++) {
            const int id = idarr[qi];           // wave-uniform
            if (id < 0) continue;
            unsigned long long m0 = __ballot(qd0 == id);
            unsigned long long m1 = __ballot(qd1 == id);
            unsigned long long m2 = __ballot(qd2 == id);
            unsigned long long m3 = __ballot(qd3 == id);
            int cnt = __popcll(m0) + __popcll(m1) + __popcll(m2) + __popcll(m3);
            if (cnt == 0) continue;
            const int q = qg * 64 + wv * 16 + qi;
            float4 r = assoc_c[(size_t)q * (TT / 4) + lane];
            float ax = 0.0f, ay = 0.0f, az = 0.0f, aw = 0.0f;
            unsigned long long mm[4] = {m0, m1, m2, m3};
            #pragma unroll
            for (int kk = 0; kk < 4; kk++) {
                unsigned long long m = mm[kk];
                while (m) {
                    int p = kk * 64 + __builtin_ctzll(m);
                    m &= m - 1;
                    float4 vv = assoc_d[(size_t)p * (TT / 4) + lane];
                    ax += vv.x; ay += vv.y; az += vv.z; aw += vv.w;
                }
            }
            float inv = 1.0f / (float)cnt;
            float dx = r.x - ax * inv, dy = r.y - ay * inv;
            float dz = r.z - az * inv, dw = r.w - aw * inv;
            tot += dx * dx + dy * dy + dz * dz + dw * dw;
            nval += 1.0f;
        }
        float2 r2 = block_sum256x2(tot, nval, s_red2);
        if (t == 0) {
            consPart[cb * 2] = r2.x * (1.0f / TT);
            consPart[cb * 2 + 1] = r2.y;
        }
    }
}

// ---------------------------------------------------------------------------
// Kernel 3: finalize — reduce all partial arrays (≈23 KB, L2-hot), 1 block.
// ---------------------------------------------------------------------------
__global__ __launch_bounds__(256)
void k_fin(const float* __restrict__ packPart, const float2* __restrict__ bigPart,
           const float2* __restrict__ consPart, float* __restrict__ out) {
    const int t = threadIdx.x;
    __shared__ float s_red[4];
    float sc = 0, bx = 0, pr = 0, qv = 0, cm = 0;
    if (t < NBC) {
        const float* row = packPart + t * 8;
        sc = row[0]; bx = row[1]; pr = row[2]; qv = row[3]; cm = row[4];
    }
    float ss = 0, ent = 0;
    #pragma unroll
    for (int k = 0; k < BIG_BLOCKS / 256; k++) {
        float2 v = bigPart[k * 256 + t];
        ss += v.x; ent += v.y;
    }
    float cons = 0, nval = 0;
    for (int i = t; i < CONS_BLOCKS; i += 256) {
        float2 v = consPart[i];
        cons += v.x; nval += v.y;
    }
    sc = block_sum256(sc, s_red);
    bx = block_sum256(bx, s_red);
    pr = block_sum256(pr, s_red);
    qv = block_sum256(qv, s_red);
    cm = block_sum256(cm, s_red);
    ss = block_sum256(ss, s_red);
    ent = block_sum256(ent, s_red);
    cons = block_sum256(cons, s_red);
    nval = block_sum256(nval, s_red);
    if (t == 0) {
        float det_norm = ss / (float)((long)BB * CC * QQ * DD);
        float denom_cam = fmaxf(cm * (float)QQ, 1.0f);
        float score_loss = sc / denom_cam;
        float box_loss = bx / fmaxf(4.0f * qv, 1.0f);
        float det_sup = score_loss + box_loss;
        float ent_loss = ent / denom_cam;
        float pair_loss = pr / fmaxf(qv, 1.0f);
        float cons_loss = cons / fmaxf(nval, 1.0f);
        out[0] = det_norm + det_sup + ent_loss + pair_loss + cons_loss;
        out[1] = det_norm;
        out[2] = det_sup;
        out[3] = ent_loss;
        out[4] = pair_loss;
        out[5] = cons_loss;
    }
}

extern "C" void kernel_launch(void* const* d_in, const int* in_sizes, int n_in,
                              void* d_out, int out_size, void* d_ws, size_t ws_size,
                              hipStream_t stream) {
    const float* det_tokens = (const float*)d_in[0];
    const float* det_scores = (const float*)d_in[1];
    const float* det_boxes  = (const float*)d_in[2];
    const float* assoc      = (const float*)d_in[3];
    const float* boxes      = (const float*)d_in[4];
    const void*  cam_raw    = d_in[5];
    const void*  tm_raw     = d_in[6];
    const int*   ids        = (const int*)d_in[7];
    const int*   img_h      = (const int*)d_in[8];
    const int*   img_w      = (const int*)d_in[9];

    char* ws = (char*)d_ws;
    int* qids            = (int*)(ws + 0);
    unsigned char* cam_c = (unsigned char*)(ws + 98304);
    float* packPart      = (float*)(ws + 98432);
    float* bigPart       = (float*)(ws + 101504);
    float* consPart      = (float*)(ws + 113792);

    k_pack<<<NBC, 256, 0, stream>>>(det_scores, det_boxes, assoc, boxes,
                                    cam_raw, tm_raw, ids, img_h, img_w,
                                    cam_c, qids, packPart);
    k_main<<<MAIN_BLOCKS, 256, 0, stream>>>((const float4*)det_tokens, assoc,
                                            cam_c, qids, bigPart, consPart);
    k_fin<<<1, 256, 0, stream>>>(packPart, (const float2*)bigPart,
                                 (const float2*)consPart, (float*)d_out);
}

// Round 7
// 112.374 us; speedup vs baseline: 2.9713x; 1.0434x over previous
//
#include <hip/hip_runtime.h>
#include <math.h>

#define BB 16
#define CC 6
#define QQ 256
#define TT 256
#define DD 256
#define NPAIR 15                      // C*(C-1)/2 for C=6
#define NBC (BB * CC)                 // 96
#define CONS_BLOCKS (BB * NPAIR * 4)  // 960  (blocks [0, 960))
#define PACK_BLOCKS NBC               // 96   (blocks [960, 1056))
#define BIG_BLOCKS (NBC * 8)          // 768  (blocks [1056, 1824)) — 2048 float4/block
#define MAIN_BLOCKS (CONS_BLOCKS + PACK_BLOCKS + BIG_BLOCKS)  // 1824 ≤ 2048 co-resident

// ws layout (bytes) — disjoint plain stores only; consumed by k_fin across the
// kernel boundary. (R4: device __threadfence = L2 writeback, ~100us/grid.
// R5: same-line float atomics from 2.5k blocks serialize, +35us. Disjoint
// stores + kernel boundary is the free path on gfx950.)
//   [0,     3072)  packPart float[96*8]   (score,box,pair,qv,cam per bc)
//   [4096, 10240)  bigPart  float[768*2]  (ss, ent per block)
//   [16384,24064)  consPart float[960*2]  (cons, nval per block)

__device__ __forceinline__ float block_sum256(float v, float* s_red) {
    #pragma unroll
    for (int off = 32; off > 0; off >>= 1) v += __shfl_xor(v, off, 64);
    __syncthreads();
    if ((threadIdx.x & 63) == 0) s_red[threadIdx.x >> 6] = v;
    __syncthreads();
    return s_red[0] + s_red[1] + s_red[2] + s_red[3];
}

// two values reduced with a single pair of barriers
__device__ __forceinline__ float2 block_sum256x2(float a, float b, float2* s_red2) {
    #pragma unroll
    for (int off = 32; off > 0; off >>= 1) {
        a += __shfl_xor(a, off, 64);
        b += __shfl_xor(b, off, 64);
    }
    __syncthreads();
    if ((threadIdx.x & 63) == 0) s_red2[threadIdx.x >> 6] = make_float2(a, b);
    __syncthreads();
    float2 r;
    r.x = s_red2[0].x + s_red2[1].x + s_red2[2].x + s_red2[3].x;
    r.y = s_red2[0].y + s_red2[1].y + s_red2[2].y + s_red2[3].y;
    return r;
}

__device__ __forceinline__ int read_bool(const void* p, int idx, int fmt) {
    if (fmt == 2) return ((const float*)p)[idx] != 0.0f;
    if (fmt == 1) return ((const unsigned char*)p)[idx] != 0;
    return ((const int*)p)[idx] != 0;
}

// Block-uniform bool-storage-format detection from the first 4096 bytes of
// target_mask (valid window in all 3 formats; L2-hot — every block reads the
// same 4 KB). 2=float32, 1=uint8, 0=int32.
__device__ __forceinline__ int detect_fmt(const void* tm_raw, int* s_cf, int* s_cm) {
    const int t = threadIdx.x;
    if (t == 0) { *s_cf = 0; *s_cm = 0; }
    __syncthreads();
    uint4 w = ((const uint4*)tm_raw)[t];
    unsigned int u4[4] = {w.x, w.y, w.z, w.w};
    int cf = 0, cm = 0;
    #pragma unroll
    for (int k = 0; k < 4; k++) {
        cf += ((u4[k] >> 24) == 0x3Fu);          // 1.0f high byte
        cm += ((u4[k] & 0xFFFFFF00u) != 0u);     // nonzero misaligned byte
    }
    if (cf) atomicAdd(s_cf, cf);
    if (cm) atomicAdd(s_cm, cm);
    __syncthreads();
    return (*s_cf > 16) ? 2 : ((*s_cm > 0) ? 1 : 0);
}

// Block-wide stable targets-first pack of camera bc. Writes qid of packed
// slot t to s_out[t]; returns target count. Uses s_sids as scratch.
__device__ __forceinline__ int block_pack(const void* tm_raw,
                                          const int* __restrict__ ids,
                                          int bc, int fmt, int cam,
                                          int* s_sids, int* s_wsum,
                                          int* s_out) {
    const int t = threadIdx.x, lane = t & 63, wv = t >> 6;
    const int tm = read_bool(tm_raw, bc * QQ + t, fmt);
    int v = tm;
    #pragma unroll
    for (int off = 1; off < 64; off <<= 1) {
        int u = __shfl_up(v, off, 64);
        if (lane >= off) v += u;
    }
    if (lane == 63) s_wsum[wv] = v;
    __syncthreads();
    const int count = s_wsum[0] + s_wsum[1] + s_wsum[2] + s_wsum[3];
    int woff = 0;
    #pragma unroll
    for (int k = 0; k < 3; k++) woff += (k < wv) ? s_wsum[k] : 0;
    const int excl = woff + v - tm;                      // exclusive scan of tm
    const int rank = tm ? excl : (count + (t - excl));   // stable partition rank
    s_sids[rank] = ids[bc * QQ + t];
    __syncthreads();
    s_out[t] = (t < count && cam) ? s_sids[t] : -1;
    __syncthreads();                                     // s_sids reusable after
    return count;
}

// ---------------------------------------------------------------------------
// Kernel 1: EVERYTHING except the final scalar combine, one dispatch:
//   [0, 960):     consistency term (pack recomputed locally — no dependency)
//   [960, 1056):  per-(b,c) pack losses (score/box/pair)
//   [1056, 1824): det_norm ss + cam-masked entropy (2048-float4 chunks)
// ---------------------------------------------------------------------------
__global__ __launch_bounds__(256)
void k_main(const float4* __restrict__ tok,
            const float* __restrict__ assoc,
            const float* __restrict__ det_scores,
            const float* __restrict__ det_boxes,
            const float* __restrict__ boxes,
            const void* __restrict__ cam_raw,
            const void* __restrict__ tm_raw,
            const int* __restrict__ ids,
            const int* __restrict__ img_h_p,
            const int* __restrict__ img_w_p,
            float* __restrict__ packPart,
            float* __restrict__ bigPart,
            float* __restrict__ consPart) {
    const int blk = blockIdx.x;
    const int t = threadIdx.x, lane = t & 63, wv = t >> 6;
    __shared__ int s_cf, s_cm;
    __shared__ float2 s_red2[4];

    if (blk >= CONS_BLOCKS + PACK_BLOCKS) {
        // ---- big phase: 2048 float4s of tok & assoc ----
        const int bb = blk - (CONS_BLOCKS + PACK_BLOCKS);
        const int bc = bb >> 3;
        const long base = (long)bc * 16384 + (long)(bb & 7) * 2048 + t;
        const float4* asc = (const float4*)assoc;
        const int fmt = detect_fmt(tm_raw, &s_cf, &s_cm);
        const int cam = read_bool(cam_raw, bc, fmt);

        float ss = 0.0f, ent = 0.0f;
        #pragma unroll
        for (int h = 0; h < 2; h++) {
            const long o = base + h * 1024;
            float4 t0 = tok[o], t1 = tok[o + 256], t2 = tok[o + 512], t3 = tok[o + 768];
            float4 a0 = asc[o], a1 = asc[o + 256], a2 = asc[o + 512], a3 = asc[o + 768];
            ss += t0.x * t0.x + t0.y * t0.y + t0.z * t0.z + t0.w * t0.w
                + t1.x * t1.x + t1.y * t1.y + t1.z * t1.z + t1.w * t1.w
                + t2.x * t2.x + t2.y * t2.y + t2.z * t2.z + t2.w * t2.w
                + t3.x * t3.x + t3.y * t3.y + t3.z * t3.z + t3.w * t3.w;
            if (cam) {                            // block-uniform branch
                ent -= a0.x * __logf(fmaxf(a0.x, 1e-8f)) + a0.y * __logf(fmaxf(a0.y, 1e-8f))
                     + a0.z * __logf(fmaxf(a0.z, 1e-8f)) + a0.w * __logf(fmaxf(a0.w, 1e-8f));
                ent -= a1.x * __logf(fmaxf(a1.x, 1e-8f)) + a1.y * __logf(fmaxf(a1.y, 1e-8f))
                     + a1.z * __logf(fmaxf(a1.z, 1e-8f)) + a1.w * __logf(fmaxf(a1.w, 1e-8f));
                ent -= a2.x * __logf(fmaxf(a2.x, 1e-8f)) + a2.y * __logf(fmaxf(a2.y, 1e-8f))
                     + a2.z * __logf(fmaxf(a2.z, 1e-8f)) + a2.w * __logf(fmaxf(a2.w, 1e-8f));
                ent -= a3.x * __logf(fmaxf(a3.x, 1e-8f)) + a3.y * __logf(fmaxf(a3.y, 1e-8f))
                     + a3.z * __logf(fmaxf(a3.z, 1e-8f)) + a3.w * __logf(fmaxf(a3.w, 1e-8f));
            }
        }
        float2 r = block_sum256x2(ss, ent, s_red2);
        if (t == 0) { bigPart[bb * 2] = r.x; bigPart[bb * 2 + 1] = r.y; }

    } else if (blk >= CONS_BLOCKS) {
        // ---- pack-loss phase: one block per (b,c) ----
        const int bc = blk - CONS_BLOCKS;
        __shared__ int s_sids[QQ], s_qid[QQ], s_wsum[4];
        const int fmt = detect_fmt(tm_raw, &s_cf, &s_cm);
        const int cam = read_bool(cam_raw, bc, fmt);
        const int count = block_pack(tm_raw, ids, bc, fmt, cam, s_sids, s_wsum, s_qid);
        // recover this thread's original-query rank for the box term:
        // (recompute tm + scan result is gone; rank = position of t in s_qid?
        //  cheaper: redo the scan pieces we need from s_qid is not possible —
        //  instead recompute tm and rank directly)
        const int tm = read_bool(tm_raw, bc * QQ + t, fmt);
        int v = tm;
        #pragma unroll
        for (int off = 1; off < 64; off <<= 1) {
            int u = __shfl_up(v, off, 64);
            if (lane >= off) v += u;
        }
        // s_wsum still holds per-wave totals from block_pack (same tm data)
        int woff = 0;
        #pragma unroll
        for (int k = 0; k < 3; k++) woff += (k < wv) ? s_wsum[k] : 0;
        const int excl = woff + v - tm;
        const int rank = tm ? excl : (count + (t - excl));

        const int j = t;                       // packed slot for score/pair
        const int qv = (j < count) && cam;
        const int qid = s_qid[j];

        float score_sum = 0.0f, box_sum = 0.0f, pair_sum = 0.0f;
        if (cam) {
            float p = det_scores[(size_t)bc * QQ + j];
            p = fminf(fmaxf(p, 1e-6f), 1.0f - 1e-6f);
            score_sum = (j < count) ? -__logf(p) : -__logf(1.0f - p);
        }
        if (qv) {
            int slot = qid & (TT - 1);
            float a = assoc[((size_t)bc * QQ + j) * TT + slot];
            pair_sum = -__logf(fmaxf(a, 1e-8f));
        }
        if (tm && cam) {
            const int jj = rank;               // packed slot of original query t
            const float iw = (float)img_w_p[0], ih = (float)img_h_p[0];
            const float* bx = boxes + ((size_t)bc * QQ + t) * 4;
            const float* db = det_boxes + ((size_t)bc * QQ + jj) * 4;
            float b0 = fminf(fmaxf(bx[0] / iw, 0.0f), 1.0f);
            float b1 = fminf(fmaxf(bx[1] / ih, 0.0f), 1.0f);
            float b2 = fminf(fmaxf(bx[2] / iw, 0.0f), 1.0f);
            float b3 = fminf(fmaxf(bx[3] / ih, 0.0f), 1.0f);
            box_sum = fabsf(db[0] - b0) + fabsf(db[1] - b1) +
                      fabsf(db[2] - b2) + fabsf(db[3] - b3);
        }
        float2 r1 = block_sum256x2(score_sum, box_sum, s_red2);
        float2 r2 = block_sum256x2(pair_sum, 0.0f, s_red2);
        if (t == 0) {
            float* row = packPart + bc * 8;
            row[0] = r1.x; row[1] = r1.y; row[2] = r2.x;
            row[3] = cam ? (float)count : 0.0f;
            row[4] = (float)cam;
        }

    } else {
        // ---- cons phase: one block per (b, pair, qgroup-of-64) ----
        const int cb = blk;
        const int qg = cb & 3;
        const int bp = cb >> 2;             // b*NPAIR + pair
        const int b = bp / NPAIR;
        int pi = bp % NPAIR;
        int c = 0, d = 1;
        {
            int k = pi;
            for (c = 0; c < CC - 1; c++) {
                int span = CC - 1 - c;
                if (k < span) { d = c + 1 + k; break; }
                k -= span;
            }
        }
        __shared__ int s_sids[QQ], s_qc[QQ], s_qd[QQ], s_wsum[4];
        const int fmt = detect_fmt(tm_raw, &s_cf, &s_cm);
        const int cam_c = read_bool(cam_raw, b * CC + c, fmt);
        const int cam_d = read_bool(cam_raw, b * CC + d, fmt);
        block_pack(tm_raw, ids, b * CC + c, fmt, cam_c, s_sids, s_wsum, s_qc);
        block_pack(tm_raw, ids, b * CC + d, fmt, cam_d, s_sids, s_wsum, s_qd);

        const int qd0 = s_qd[lane];
        const int qd1 = s_qd[64 + lane];
        const int qd2 = s_qd[128 + lane];
        const int qd3 = s_qd[192 + lane];
        int idarr[16];
        #pragma unroll
        for (int qi = 0; qi < 16; qi++) idarr[qi] = s_qc[qg * 64 + wv * 16 + qi];

        const float4* assoc_c = (const float4*)(assoc + (size_t)(b * CC + c) * QQ * TT);
        const float4* assoc_d = (const float4*)(assoc + (size_t)(b * CC + d) * QQ * TT);

        float tot = 0.0f, nval = 0.0f;
        #pragma unroll 4
        for (int qi = 0; qi < 16; qi++) {
            const int id = idarr[qi];           // wave-uniform
            if (id < 0) continue;
            unsigned long long m0 = __ballot(qd0 == id);
            unsigned long long m1 = __ballot(qd1 == id);
            unsigned long long m2 = __ballot(qd2 == id);
            unsigned long long m3 = __ballot(qd3 == id);
            int cnt = __popcll(m0) + __popcll(m1) + __popcll(m2) + __popcll(m3);
            if (cnt == 0) continue;
            const int q = qg * 64 + wv * 16 + qi;
            float4 r = assoc_c[(size_t)q * (TT / 4) + lane];
            float ax = 0.0f, ay = 0.0f, az = 0.0f, aw = 0.0f;
            unsigned long long mm[4] = {m0, m1, m2, m3};
            #pragma unroll
            for (int kk = 0; kk < 4; kk++) {
                unsigned long long m = mm[kk];
                while (m) {
                    int p = kk * 64 + __builtin_ctzll(m);
                    m &= m - 1;
                    float4 vv = assoc_d[(size_t)p * (TT / 4) + lane];
                    ax += vv.x; ay += vv.y; az += vv.z; aw += vv.w;
                }
            }
            float inv = 1.0f / (float)cnt;
            float dx = r.x - ax * inv, dy = r.y - ay * inv;
            float dz = r.z - az * inv, dw = r.w - aw * inv;
            tot += dx * dx + dy * dy + dz * dz + dw * dw;
            nval += 1.0f;
        }
        float2 r2 = block_sum256x2(tot, nval, s_red2);
        if (t == 0) {
            consPart[cb * 2] = r2.x * (1.0f / TT);
            consPart[cb * 2 + 1] = r2.y;
        }
    }
}

// ---------------------------------------------------------------------------
// Kernel 2: finalize — reduce all partial arrays (~17 KB, L2-hot), 1 block.
// ---------------------------------------------------------------------------
__global__ __launch_bounds__(256)
void k_fin(const float* __restrict__ packPart, const float2* __restrict__ bigPart,
           const float2* __restrict__ consPart, float* __restrict__ out) {
    const int t = threadIdx.x;
    __shared__ float s_red[4];
    float sc = 0, bx = 0, pr = 0, qv = 0, cm = 0;
    if (t < NBC) {
        const float* row = packPart + t * 8;
        sc = row[0]; bx = row[1]; pr = row[2]; qv = row[3]; cm = row[4];
    }
    float ss = 0, ent = 0;
    #pragma unroll
    for (int k = 0; k < BIG_BLOCKS / 256; k++) {
        float2 v = bigPart[k * 256 + t];
        ss += v.x; ent += v.y;
    }
    float cons = 0, nval = 0;
    for (int i = t; i < CONS_BLOCKS; i += 256) {
        float2 v = consPart[i];
        cons += v.x; nval += v.y;
    }
    sc = block_sum256(sc, s_red);
    bx = block_sum256(bx, s_red);
    pr = block_sum256(pr, s_red);
    qv = block_sum256(qv, s_red);
    cm = block_sum256(cm, s_red);
    ss = block_sum256(ss, s_red);
    ent = block_sum256(ent, s_red);
    cons = block_sum256(cons, s_red);
    nval = block_sum256(nval, s_red);
    if (t == 0) {
        float det_norm = ss / (float)((long)BB * CC * QQ * DD);
        float denom_cam = fmaxf(cm * (float)QQ, 1.0f);
        float score_loss = sc / denom_cam;
        float box_loss = bx / fmaxf(4.0f * qv, 1.0f);
        float det_sup = score_loss + box_loss;
        float ent_loss = ent / denom_cam;
        float pair_loss = pr / fmaxf(qv, 1.0f);
        float cons_loss = cons / fmaxf(nval, 1.0f);
        out[0] = det_norm + det_sup + ent_loss + pair_loss + cons_loss;
        out[1] = det_norm;
        out[2] = det_sup;
        out[3] = ent_loss;
        out[4] = pair_loss;
        out[5] = cons_loss;
    }
}

extern "C" void kernel_launch(void* const* d_in, const int* in_sizes, int n_in,
                              void* d_out, int out_size, void* d_ws, size_t ws_size,
                              hipStream_t stream) {
    const float* det_tokens = (const float*)d_in[0];
    const float* det_scores = (const float*)d_in[1];
    const float* det_boxes  = (const float*)d_in[2];
    const float* assoc      = (const float*)d_in[3];
    const float* boxes      = (const float*)d_in[4];
    const void*  cam_raw    = d_in[5];
    const void*  tm_raw     = d_in[6];
    const int*   ids        = (const int*)d_in[7];
    const int*   img_h      = (const int*)d_in[8];
    const int*   img_w      = (const int*)d_in[9];

    char* ws = (char*)d_ws;
    float* packPart = (float*)(ws + 0);
    float* bigPart  = (float*)(ws + 4096);
    float* consPart = (float*)(ws + 16384);

    k_main<<<MAIN_BLOCKS, 256, 0, stream>>>((const float4*)det_tokens, assoc,
                                            det_scores, det_boxes, boxes,
                                            cam_raw, tm_raw, ids, img_h, img_w,
                                            packPart, bigPart, consPart);
    k_fin<<<1, 256, 0, stream>>>(packPart, (const float2*)bigPart,
                                 (const float2*)consPart, (float*)d_out);
}